// Round 1
// baseline (189.922 us; speedup 1.0000x reference)
//
#include <hip/hip_runtime.h>

// Problem constants (from reference): B=64, S=8192, C=512
#define NROWS (64 * 8192)
#define C 512
#define WEIGHT 2.0f
#define NBLOCKS 2048
#define BLOCK 256  // 4 waves per block

// One wave (64 lanes) per row. Each lane loads 2x float4 = 8 floats of the
// 512-float row (coalesced: float4 index lane, then 64+lane). Lane-local
// argmax (first occurrence), then 6-step shfl_xor butterfly argmax reduce
// (tie-break: smaller index wins -> matches jnp.argmax). Gathered value via
// broadcast load from the just-fetched row (L1 hit). Per-block partial sums
// written to workspace; deterministic second-pass reduction.
__global__ __launch_bounds__(BLOCK) void nll_rows_kernel(
    const float* __restrict__ pre,
    const int* __restrict__ y_true,
    float* __restrict__ partial) {
    const int lane = threadIdx.x & 63;
    const int wave = threadIdx.x >> 6;           // 0..3
    const int gwave = blockIdx.x * 4 + wave;     // global wave id
    const int nwaves = gridDim.x * 4;

    float acc = 0.0f;

    for (int row = gwave; row < NROWS; row += nwaves) {
        const float4* rowp = reinterpret_cast<const float4*>(pre + (size_t)row * C);
        float4 a = rowp[lane];        // cols [4*lane, 4*lane+4)
        float4 b = rowp[64 + lane];   // cols [256+4*lane, 256+4*lane+4)

        // Lane-local argmax, ascending column order, strict > => first occurrence.
        int baseA = lane * 4;
        float mval = a.x; int midx = baseA;
        if (a.y > mval) { mval = a.y; midx = baseA + 1; }
        if (a.z > mval) { mval = a.z; midx = baseA + 2; }
        if (a.w > mval) { mval = a.w; midx = baseA + 3; }
        int baseB = 256 + lane * 4;
        if (b.x > mval) { mval = b.x; midx = baseB; }
        if (b.y > mval) { mval = b.y; midx = baseB + 1; }
        if (b.z > mval) { mval = b.z; midx = baseB + 2; }
        if (b.w > mval) { mval = b.w; midx = baseB + 3; }

        // Wave-wide argmax reduce; on ties prefer the smaller column index.
        #pragma unroll
        for (int off = 1; off < 64; off <<= 1) {
            float oval = __shfl_xor(mval, off);
            int   oidx = __shfl_xor(midx, off);
            if (oval > mval || (oval == mval && oidx < midx)) {
                mval = oval; midx = oidx;
            }
        }

        int t = y_true[row];                         // broadcast load
        float g = pre[(size_t)row * C + t];          // L1 hit (row just read)
        int d = midx - t;
        float w = (d == 1 || d == -1) ? WEIGHT : 1.0f;
        if (lane == 0) acc += w * g;
    }

    __shared__ float ssum[4];
    if (lane == 0) ssum[wave] = acc;
    __syncthreads();
    if (threadIdx.x == 0) {
        partial[blockIdx.x] = ssum[0] + ssum[1] + ssum[2] + ssum[3];
    }
}

// Deterministic fixed-order reduction of the block partials.
__global__ __launch_bounds__(256) void nll_reduce_kernel(
    const float* __restrict__ partial, float* __restrict__ out, int n) {
    __shared__ float s[256];
    float acc = 0.0f;
    for (int i = threadIdx.x; i < n; i += 256) acc += partial[i];
    s[threadIdx.x] = acc;
    __syncthreads();
    for (int w = 128; w > 0; w >>= 1) {
        if (threadIdx.x < w) s[threadIdx.x] += s[threadIdx.x + w];
        __syncthreads();
    }
    if (threadIdx.x == 0) out[0] = s[0] * (1.0f / 64.0f);  // divide by B
}

extern "C" void kernel_launch(void* const* d_in, const int* in_sizes, int n_in,
                              void* d_out, int out_size, void* d_ws, size_t ws_size,
                              hipStream_t stream) {
    const float* pre = (const float*)d_in[0];
    const int* y_true = (const int*)d_in[1];
    float* out = (float*)d_out;
    float* partial = (float*)d_ws;  // NBLOCKS floats

    nll_rows_kernel<<<NBLOCKS, BLOCK, 0, stream>>>(pre, y_true, partial);
    nll_reduce_kernel<<<1, 256, 0, stream>>>(partial, out, NBLOCKS);
}